// Round 1
// baseline (1926.704 us; speedup 1.0000x reference)
//
#include <hip/hip_runtime.h>
#include <math.h>

// ---------------------------------------------------------------------------
// Hyena forward, MI355X.  B=2, L=8192, C=1024, ORDER=2.
// Key simplification: reference loop overwrites `output`, so only branch i=1
// (proj[...,2]) and filter column (2c+1) matter.  proj[...,1] is dead.
// FFT conv: batches packed as re/im of one complex 16384-pt FFT per channel;
// DIF fwd + DIT inv (no bit reversal needed); H spectrum kept in registers.
// ---------------------------------------------------------------------------

constexpr int Lseq = 8192;
constexpr int Cd   = 1024;
constexpr int BL   = 16384;   // B * L
constexpr int NF   = 16384;   // FFT length = 2L

// workspace layout (float offsets)
constexpr size_t VT_OFF   = 0;                               // v_t   [C][B][L]
constexpr size_t X2_OFF   = VT_OFF   + (size_t)Cd * BL;      // gate_t[C][B][L] (overwritten w/ gate*conv)
constexpr size_t COEF_OFF = X2_OFF   + (size_t)Cd * BL;      // coefs_t [C][L]
constexpr size_t H2_OFF   = COEF_OFF + (size_t)Cd * Lseq;    // h2 [L][128]
constexpr size_t W2_OFF   = H2_OFF   + (size_t)Lseq * 128;   // compacted in_proj_w [1024][2048]
constexpr size_t B2_OFF   = W2_OFF   + (size_t)1024 * 2048;  // compacted bias [2048]
constexpr size_t WS_FLOATS = B2_OFF + 2048;
constexpr size_t WS_BYTES  = WS_FLOATS * 4;                  // ~180.4 MB

// ---------------------------------------------------------------------------
// complex helpers
__device__ inline float2 cadd(float2 a, float2 b){ return make_float2(a.x+b.x, a.y+b.y); }
__device__ inline float2 csub(float2 a, float2 b){ return make_float2(a.x-b.x, a.y-b.y); }
__device__ inline float2 cmul(float2 a, float2 b){ return make_float2(a.x*b.x - a.y*b.y, a.x*b.y + a.y*b.x); }
// a * conj(w)
__device__ inline float2 cmulc(float2 a, float2 w){ return make_float2(a.x*w.x + a.y*w.y, a.y*w.x - a.x*w.y); }

// W_N^m = e^{-2*pi*i*m/N}, m in [0, N).  T holds (cos,sin) for k = 0..2048.
__device__ inline float2 twget(const float2* __restrict__ T, int m) {
  int q = (m >> 12) & 3;
  int r = m & 4095;
  bool lo = (r < 2048);
  int k = lo ? r : 4096 - r;
  float2 e = T[k];
  float c = lo ? e.x : e.y;
  float s = lo ? e.y : e.x;
  float2 w = make_float2(c, -s);              // e^{-i*theta_r}
  if      (q == 1) w = make_float2( w.y, -w.x);   // * (-i)
  else if (q == 2) w = make_float2(-w.x, -w.y);   // * (-1)
  else if (q == 3) w = make_float2(-w.y,  w.x);   // * (+i)
  return w;
}

// radix-4 DIF, natural in -> digit-reversed out.  512 threads.
__device__ inline void fftDIF(float2* __restrict__ z, const float2* __restrict__ T, int t) {
  for (int lq = 12; lq >= 0; lq -= 2) {
    int q    = 1 << lq;
    int twsh = 12 - lq;
    #pragma unroll
    for (int mb = 0; mb < 8; ++mb) {
      int m    = t + mb * 512;
      int tloc = m & (q - 1);
      int g    = m >> lq;
      int base = (g << (lq + 2)) + tloc;
      float2 a = z[base], b = z[base + q], c = z[base + 2*q], d = z[base + 3*q];
      float2 t0 = cadd(a, c), t1 = csub(a, c);
      float2 t2 = cadd(b, d), t3 = csub(b, d);
      float2 y0 = cadd(t0, t2);
      float2 y2 = csub(t0, t2);
      float2 y1 = make_float2(t1.x + t3.y, t1.y - t3.x);   // t1 - i*t3
      float2 y3 = make_float2(t1.x - t3.y, t1.y + t3.x);   // t1 + i*t3
      int m1 = tloc << twsh;
      z[base]         = y0;
      z[base + q]     = cmul(y1, twget(T, m1));
      z[base + 2*q]   = cmul(y2, twget(T, 2*m1));
      z[base + 3*q]   = cmul(y3, twget(T, 3*m1));
    }
    __syncthreads();
  }
}

// radix-4 DIT inverse (digit-reversed in -> natural out), unscaled (x N).
__device__ inline void fftDIT(float2* __restrict__ z, const float2* __restrict__ T, int t) {
  for (int lq = 0; lq <= 12; lq += 2) {
    int q    = 1 << lq;
    int twsh = 12 - lq;
    #pragma unroll
    for (int mb = 0; mb < 8; ++mb) {
      int m    = t + mb * 512;
      int tloc = m & (q - 1);
      int g    = m >> lq;
      int base = (g << (lq + 2)) + tloc;
      int m1 = tloc << twsh;
      float2 a = z[base];
      float2 b = cmulc(z[base + q],   twget(T, m1));
      float2 c = cmulc(z[base + 2*q], twget(T, 2*m1));
      float2 d = cmulc(z[base + 3*q], twget(T, 3*m1));
      float2 s0 = cadd(a, c), s1 = csub(a, c);
      float2 s2 = cadd(b, d), s3 = csub(b, d);
      z[base]       = cadd(s0, s2);
      z[base + q]   = make_float2(s1.x - s3.y, s1.y + s3.x);  // s1 + i*s3
      z[base + 2*q] = csub(s0, s2);
      z[base + 3*q] = make_float2(s1.x + s3.y, s1.y - s3.x);  // s1 - i*s3
    }
    __syncthreads();
  }
}

// ---------------------------------------------------------------------------
// 1) compact in_proj weights: keep cols 3c (v) and 3c+2 (gate)
__global__ void compact_w_kernel(const float* __restrict__ w, const float* __restrict__ b,
                                 float* __restrict__ w2, float* __restrict__ b2) {
  int g = blockIdx.x * blockDim.x + threadIdx.x;
  if (g < 1024 * 2048) {
    int k = g >> 11;
    int n = g & 2047;
    int src = (n < 1024) ? 3 * n : 3 * (n - 1024) + 2;
    w2[g] = w[(size_t)k * 3072 + src];
  }
  int gb = g - 1024 * 2048;
  if (gb >= 0 && gb < 2048) {
    int src = (gb < 1024) ? 3 * gb : 3 * (gb - 1024) + 2;
    b2[gb] = b[src];
  }
}

// ---------------------------------------------------------------------------
// 2) filter MLP trunk: h2[l][m] = gelu(gelu(pos*fw1+fb1) @ fw2 + fb2)
__global__ __launch_bounds__(256) void mlp_kernel(const float* __restrict__ fw1, const float* __restrict__ fb1,
                                                  const float* __restrict__ fw2, const float* __restrict__ fb2,
                                                  float* __restrict__ h2) {
  __shared__ float sw2[64 * 128];
  __shared__ float sw1[64], sb1[64], sb2[128];
  int t = threadIdx.x;
  for (int i = t; i < 64 * 128; i += 256) sw2[i] = fw2[i];
  if (t < 64)  { sw1[t] = fw1[t]; sb1[t] = fb1[t]; }
  if (t < 128) sb2[t] = fb2[t];
  __syncthreads();
  int l = blockIdx.x * 256 + t;
  float pos = (float)l / 8191.0f;
  float h1[64];
  #pragma unroll
  for (int j = 0; j < 64; ++j) {
    float xx = pos * sw1[j] + sb1[j];
    h1[j] = 0.5f * xx * (1.0f + erff(xx * 0.7071067811865475f));
  }
  for (int m = 0; m < 128; ++m) {
    float acc = sb2[m];
    #pragma unroll
    for (int j = 0; j < 64; ++j) acc += h1[j] * sw2[j * 128 + m];
    h2[(size_t)l * 128 + m] = 0.5f * acc * (1.0f + erff(acc * 0.7071067811865475f));
  }
}

// ---------------------------------------------------------------------------
// 3) in_proj GEMM: X(16384x1024) @ W2(1024x2048) + b2 -> v_t / gate_t (transposed)
__global__ __launch_bounds__(256) void gemm_in_kernel(const float* __restrict__ X,
    const float* __restrict__ W2, const float* __restrict__ B2,
    float* __restrict__ vt, float* __restrict__ x2t) {
  __shared__ float As[16 * 72];
  __shared__ float Bs[16 * 72];
  int t  = threadIdx.x;
  int n0 = blockIdx.x * 64;
  int m0 = blockIdx.y * 64;
  int tr = t >> 4, tc = t & 15;
  float acc[4][4] = {};
  int am = t >> 2, ak = (t & 3) * 4;
  int bk = t >> 4, bn = (t & 15) * 4;
  for (int k0 = 0; k0 < 1024; k0 += 16) {
    float4 a = *(const float4*)&X[(size_t)(m0 + am) * 1024 + k0 + ak];
    float4 b = *(const float4*)&W2[(size_t)(k0 + bk) * 2048 + n0 + bn];
    __syncthreads();
    As[(ak + 0) * 72 + am] = a.x;
    As[(ak + 1) * 72 + am] = a.y;
    As[(ak + 2) * 72 + am] = a.z;
    As[(ak + 3) * 72 + am] = a.w;
    *(float4*)&Bs[bk * 72 + bn] = b;
    __syncthreads();
    #pragma unroll
    for (int kk = 0; kk < 16; ++kk) {
      float4 av = *(const float4*)&As[kk * 72 + tr * 4];
      float4 bv = *(const float4*)&Bs[kk * 72 + tc * 4];
      float aa[4] = {av.x, av.y, av.z, av.w};
      float bb[4] = {bv.x, bv.y, bv.z, bv.w};
      #pragma unroll
      for (int i = 0; i < 4; ++i)
        #pragma unroll
        for (int j = 0; j < 4; ++j)
          acc[i][j] += aa[i] * bb[j];
    }
  }
  #pragma unroll
  for (int j = 0; j < 4; ++j) {
    int n = n0 + tc * 4 + j;
    float bias = B2[n];
    float* dst = (n < 1024) ? (vt + (size_t)n * BL) : (x2t + (size_t)(n - 1024) * BL);
    float4 val = make_float4(acc[0][j] + bias, acc[1][j] + bias, acc[2][j] + bias, acc[3][j] + bias);
    *(float4*)&dst[m0 + tr * 4] = val;
  }
}

// ---------------------------------------------------------------------------
// 4) coef GEMM: h2(8192x128) @ fw3[:,2c+1](128x1024) + fb3[2c+1] -> coefs_t[c][l]
__global__ __launch_bounds__(256) void gemm_coefs_kernel(const float* __restrict__ H2,
    const float* __restrict__ FW3, const float* __restrict__ FB3,
    float* __restrict__ coefs) {
  __shared__ float As[16 * 72];
  __shared__ float Bs[16 * 72];
  int t  = threadIdx.x;
  int n0 = blockIdx.x * 64;   // channel tile
  int m0 = blockIdx.y * 64;   // l tile
  int tr = t >> 4, tc = t & 15;
  float acc[4][4] = {};
  int am = t >> 2, ak = (t & 3) * 4;
  int bk = t >> 4, bn = (t & 15) * 4;
  for (int k0 = 0; k0 < 128; k0 += 16) {
    float4 a = *(const float4*)&H2[(size_t)(m0 + am) * 128 + k0 + ak];
    float b0 = FW3[(size_t)(k0 + bk) * 2048 + 2 * (n0 + bn + 0) + 1];
    float b1 = FW3[(size_t)(k0 + bk) * 2048 + 2 * (n0 + bn + 1) + 1];
    float b2 = FW3[(size_t)(k0 + bk) * 2048 + 2 * (n0 + bn + 2) + 1];
    float b3 = FW3[(size_t)(k0 + bk) * 2048 + 2 * (n0 + bn + 3) + 1];
    __syncthreads();
    As[(ak + 0) * 72 + am] = a.x;
    As[(ak + 1) * 72 + am] = a.y;
    As[(ak + 2) * 72 + am] = a.z;
    As[(ak + 3) * 72 + am] = a.w;
    Bs[bk * 72 + bn + 0] = b0;
    Bs[bk * 72 + bn + 1] = b1;
    Bs[bk * 72 + bn + 2] = b2;
    Bs[bk * 72 + bn + 3] = b3;
    __syncthreads();
    #pragma unroll
    for (int kk = 0; kk < 16; ++kk) {
      float4 av = *(const float4*)&As[kk * 72 + tr * 4];
      float4 bv = *(const float4*)&Bs[kk * 72 + tc * 4];
      float aa[4] = {av.x, av.y, av.z, av.w};
      float bb[4] = {bv.x, bv.y, bv.z, bv.w};
      #pragma unroll
      for (int i = 0; i < 4; ++i)
        #pragma unroll
        for (int j = 0; j < 4; ++j)
          acc[i][j] += aa[i] * bb[j];
    }
  }
  #pragma unroll
  for (int j = 0; j < 4; ++j) {
    int c = n0 + tc * 4 + j;
    float bias = FB3[2 * c + 1];
    float4 val = make_float4(acc[0][j] + bias, acc[1][j] + bias, acc[2][j] + bias, acc[3][j] + bias);
    *(float4*)&coefs[(size_t)c * Lseq + m0 + tr * 4] = val;
  }
}

// ---------------------------------------------------------------------------
// 5) per-channel: filter FFT (spectrum -> regs), short conv + v FFT (batches
//    packed re/im), multiply, inverse FFT, gate multiply, in-place into x2t.
__global__ __launch_bounds__(512) void conv_fft_kernel(
    const float* __restrict__ vt, float* __restrict__ x2t,
    const float* __restrict__ coefs,
    const float* __restrict__ short_w, const float* __restrict__ short_b) {
  extern __shared__ char smem[];
  float2* z = (float2*)smem;
  float2* T = (float2*)(smem + (size_t)NF * sizeof(float2));
  int t = threadIdx.x;
  int c = blockIdx.x;

  for (int k = t; k <= 2048; k += 512) {
    double ang = 6.283185307179586 * (double)k / (double)NF;
    T[k] = make_float2((float)cos(ang), (float)sin(ang));
  }
  __syncthreads();

  // ---- filter FFT
  const float* cf = coefs + (size_t)c * Lseq;
  for (int l = t; l < Lseq; l += 512)      z[l] = make_float2(cf[l], 0.f);
  for (int l = Lseq + t; l < NF; l += 512) z[l] = make_float2(0.f, 0.f);
  __syncthreads();
  fftDIF(z, T, t);

  float2 Hreg[32];
  constexpr float invN = 1.0f / (float)NF;
  #pragma unroll
  for (int j = 0; j < 32; ++j) {
    float2 h = z[t + 512 * j];
    Hreg[j] = make_float2(h.x * invN, h.y * invN);
  }
  __syncthreads();

  // ---- v: short depthwise conv (k=3, same pad), batches packed re/im
  float sw0 = short_w[c * 3 + 0], sw1 = short_w[c * 3 + 1], sw2 = short_w[c * 3 + 2];
  float sbv = short_b[c];
  const float* v0 = vt + (size_t)c * BL;
  const float* v1 = v0 + Lseq;
  for (int l = t; l < Lseq; l += 512) {
    float a0 = (l > 0)        ? v0[l - 1] : 0.f;
    float b0 = v0[l];
    float c0 = (l < Lseq - 1) ? v0[l + 1] : 0.f;
    float a1 = (l > 0)        ? v1[l - 1] : 0.f;
    float b1 = v1[l];
    float c1 = (l < Lseq - 1) ? v1[l + 1] : 0.f;
    z[l] = make_float2(sw0 * a0 + sw1 * b0 + sw2 * c0 + sbv,
                       sw0 * a1 + sw1 * b1 + sw2 * c1 + sbv);
  }
  for (int l = Lseq + t; l < NF; l += 512) z[l] = make_float2(0.f, 0.f);
  __syncthreads();
  fftDIF(z, T, t);

  #pragma unroll
  for (int j = 0; j < 32; ++j) {
    int p = t + 512 * j;
    z[p] = cmul(z[p], Hreg[j]);
  }
  __syncthreads();
  fftDIT(z, T, t);

  // ---- gate and write back in place (y = gate * conv)
  float* y0 = x2t + (size_t)c * BL;
  float* y1 = y0 + Lseq;
  for (int l = t; l < Lseq; l += 512) {
    float2 cv = z[l];
    y0[l] = y0[l] * cv.x;
    y1[l] = y1[l] * cv.y;
  }
}

// ---------------------------------------------------------------------------
// 6) out GEMM (TN): y_t^T(16384x1024) @ out_w(1024x1024) + out_b -> d_out
__global__ __launch_bounds__(256) void gemm_out_kernel(const float* __restrict__ Yt,
    const float* __restrict__ Wout, const float* __restrict__ Bout,
    float* __restrict__ out) {
  __shared__ float As[16 * 72];
  __shared__ float Bs[16 * 72];
  int t  = threadIdx.x;
  int n0 = blockIdx.x * 64;
  int m0 = blockIdx.y * 64;
  int tr = t >> 4, tc = t & 15;
  float acc[4][4] = {};
  int kr = t >> 4, mq = (t & 15) * 4;
  for (int k0 = 0; k0 < 1024; k0 += 16) {
    float4 a = *(const float4*)&Yt[(size_t)(k0 + kr) * BL + m0 + mq];
    float4 b = *(const float4*)&Wout[(size_t)(k0 + kr) * 1024 + n0 + mq];
    __syncthreads();
    *(float4*)&As[kr * 72 + mq] = a;
    *(float4*)&Bs[kr * 72 + mq] = b;
    __syncthreads();
    #pragma unroll
    for (int kk = 0; kk < 16; ++kk) {
      float4 av = *(const float4*)&As[kk * 72 + tr * 4];
      float4 bv = *(const float4*)&Bs[kk * 72 + tc * 4];
      float aa[4] = {av.x, av.y, av.z, av.w};
      float bb[4] = {bv.x, bv.y, bv.z, bv.w};
      #pragma unroll
      for (int i = 0; i < 4; ++i)
        #pragma unroll
        for (int j = 0; j < 4; ++j)
          acc[i][j] += aa[i] * bb[j];
    }
  }
  float4 ob = *(const float4*)&Bout[n0 + tc * 4];
  float obv[4] = {ob.x, ob.y, ob.z, ob.w};
  #pragma unroll
  for (int i = 0; i < 4; ++i) {
    int r = m0 + tr * 4 + i;
    float4 val = make_float4(acc[i][0] + obv[0], acc[i][1] + obv[1],
                             acc[i][2] + obv[2], acc[i][3] + obv[3]);
    *(float4*)&out[(size_t)r * 1024 + n0 + tc * 4] = val;
  }
}

// ---------------------------------------------------------------------------
extern "C" void kernel_launch(void* const* d_in, const int* in_sizes, int n_in,
                              void* d_out, int out_size, void* d_ws, size_t ws_size,
                              hipStream_t stream) {
  (void)in_sizes; (void)n_in; (void)out_size;
  const float* x    = (const float*)d_in[0];
  const float* ipw  = (const float*)d_in[1];
  const float* ipb  = (const float*)d_in[2];
  const float* sw   = (const float*)d_in[3];
  const float* sb   = (const float*)d_in[4];
  const float* fw1  = (const float*)d_in[5];
  const float* fb1  = (const float*)d_in[6];
  const float* fw2  = (const float*)d_in[7];
  const float* fb2  = (const float*)d_in[8];
  const float* fw3  = (const float*)d_in[9];
  const float* fb3  = (const float*)d_in[10];
  const float* outw = (const float*)d_in[11];
  const float* outb = (const float*)d_in[12];
  float* out = (float*)d_out;
  float* ws  = (float*)d_ws;

  if (ws_size < WS_BYTES) return;   // workspace too small: fail loudly via validation

  float* vt    = ws + VT_OFF;
  float* x2t   = ws + X2_OFF;
  float* coefs = ws + COEF_OFF;
  float* h2    = ws + H2_OFF;
  float* w2    = ws + W2_OFF;
  float* b2    = ws + B2_OFF;

  constexpr int CONV_LDS = NF * 8 + 2049 * 8;  // 131072 + 16392 = 147464 B
  hipFuncSetAttribute(reinterpret_cast<const void*>(conv_fft_kernel),
                      hipFuncAttributeMaxDynamicSharedMemorySize, CONV_LDS);

  compact_w_kernel<<<8200, 256, 0, stream>>>(ipw, ipb, w2, b2);
  mlp_kernel<<<32, 256, 0, stream>>>(fw1, fb1, fw2, fb2, h2);
  gemm_in_kernel<<<dim3(32, 256), 256, 0, stream>>>(x, w2, b2, vt, x2t);
  gemm_coefs_kernel<<<dim3(16, 128), 256, 0, stream>>>(h2, fw3, fb3, coefs);
  conv_fft_kernel<<<1024, 512, CONV_LDS, stream>>>(vt, x2t, coefs, sw, sb);
  gemm_out_kernel<<<dim3(16, 256), 256, 0, stream>>>(x2t, outw, outb, out);
}

// Round 2
// 1025.443 us; speedup vs baseline: 1.8789x; 1.8789x over previous
//
#include <hip/hip_runtime.h>
#include <math.h>

// ---------------------------------------------------------------------------
// Hyena forward, MI355X.  B=2, L=8192, C=1024, ORDER=2.
// R1: both big GEMMs -> bf16 MFMA (16x16x32) with 3-product split precision
// (hi*hi + hi*lo + lo*hi), m97-style 128x128 tile + global_load_lds staging.
// FFT conv path unchanged (fp32, batches packed re/im, DIF fwd + DIT inv).
// Workspace kept under the round-0-proven 180.4 MB by:
//   - X hi/lo bf16 lives in d_out (dead until final GEMM store)
//   - Y hi/lo bf16 overwrites the dead v region after conv_fft
//   - h2 transiently aliases the W2T region (consumed before compact_w runs)
// ---------------------------------------------------------------------------

constexpr int Lseq = 8192;
constexpr int Cd   = 1024;
constexpr int BL   = 16384;   // B * L
constexpr int NF   = 16384;   // FFT length = 2L
constexpr int KK   = 1024;    // GEMM K dim (both GEMMs)

// ws layout (float offsets)
constexpr size_t BIG_OFF  = 0;                                  // [2048][BL] fp32: rows 0-1023 v, 1024-2047 gate->y
constexpr size_t COEF_OFF = BIG_OFF + (size_t)2048 * BL;        // 33,554,432  (coefs_t [C][L])
constexpr size_t W2TH_OFF = COEF_OFF + (size_t)Cd * Lseq;       // 41,943,040  (2048x1024 ushort)
constexpr size_t W2TL_OFF = W2TH_OFF + (size_t)2048 * 1024 / 2; // 42,991,616
constexpr size_t WOTH_OFF = W2TL_OFF + (size_t)2048 * 1024 / 2; // 44,040,192  (1024x1024 ushort)
constexpr size_t WOTL_OFF = WOTH_OFF + (size_t)1024 * 1024 / 2; // 44,564,480
constexpr size_t B2_OFF   = WOTL_OFF + (size_t)1024 * 1024 / 2; // 45,088,768
constexpr size_t WS_FLOATS = B2_OFF + 2048;                     // 45,090,816 -> 180,363,264 B (<= proven 180,367,360)
// h2 [8192][128] fp32 = 1,048,576 floats aliases W2TH region (exact fit).

using bf16x8 = __attribute__((ext_vector_type(8))) short;
using f32x4  = __attribute__((ext_vector_type(4))) float;

__device__ inline unsigned short f2bf(float f) {
  unsigned u = __float_as_uint(f);
  u += 0x7FFFu + ((u >> 16) & 1u);
  return (unsigned short)(u >> 16);
}
__device__ inline float bf2f(unsigned short h) { return __uint_as_float(((unsigned)h) << 16); }

__device__ inline void gload_lds16(const void* g, void* l) {
  __builtin_amdgcn_global_load_lds((const __attribute__((address_space(1))) unsigned int*)g,
                                   (__attribute__((address_space(3))) unsigned int*)l, 16, 0, 0);
}

// ---------------------------------------------------------------------------
// complex helpers (FFT path, unchanged from R0)
__device__ inline float2 cadd(float2 a, float2 b){ return make_float2(a.x+b.x, a.y+b.y); }
__device__ inline float2 csub(float2 a, float2 b){ return make_float2(a.x-b.x, a.y-b.y); }
__device__ inline float2 cmul(float2 a, float2 b){ return make_float2(a.x*b.x - a.y*b.y, a.x*b.y + a.y*b.x); }
__device__ inline float2 cmulc(float2 a, float2 w){ return make_float2(a.x*w.x + a.y*w.y, a.y*w.x - a.x*w.y); }

__device__ inline float2 twget(const float2* __restrict__ T, int m) {
  int q = (m >> 12) & 3;
  int r = m & 4095;
  bool lo = (r < 2048);
  int k = lo ? r : 4096 - r;
  float2 e = T[k];
  float c = lo ? e.x : e.y;
  float s = lo ? e.y : e.x;
  float2 w = make_float2(c, -s);
  if      (q == 1) w = make_float2( w.y, -w.x);
  else if (q == 2) w = make_float2(-w.x, -w.y);
  else if (q == 3) w = make_float2(-w.y,  w.x);
  return w;
}

__device__ inline void fftDIF(float2* __restrict__ z, const float2* __restrict__ T, int t) {
  for (int lq = 12; lq >= 0; lq -= 2) {
    int q    = 1 << lq;
    int twsh = 12 - lq;
    #pragma unroll
    for (int mb = 0; mb < 8; ++mb) {
      int m    = t + mb * 512;
      int tloc = m & (q - 1);
      int g    = m >> lq;
      int base = (g << (lq + 2)) + tloc;
      float2 a = z[base], b = z[base + q], c = z[base + 2*q], d = z[base + 3*q];
      float2 t0 = cadd(a, c), t1 = csub(a, c);
      float2 t2 = cadd(b, d), t3 = csub(b, d);
      float2 y0 = cadd(t0, t2);
      float2 y2 = csub(t0, t2);
      float2 y1 = make_float2(t1.x + t3.y, t1.y - t3.x);
      float2 y3 = make_float2(t1.x - t3.y, t1.y + t3.x);
      int m1 = tloc << twsh;
      z[base]         = y0;
      z[base + q]     = cmul(y1, twget(T, m1));
      z[base + 2*q]   = cmul(y2, twget(T, 2*m1));
      z[base + 3*q]   = cmul(y3, twget(T, 3*m1));
    }
    __syncthreads();
  }
}

__device__ inline void fftDIT(float2* __restrict__ z, const float2* __restrict__ T, int t) {
  for (int lq = 0; lq <= 12; lq += 2) {
    int q    = 1 << lq;
    int twsh = 12 - lq;
    #pragma unroll
    for (int mb = 0; mb < 8; ++mb) {
      int m    = t + mb * 512;
      int tloc = m & (q - 1);
      int g    = m >> lq;
      int base = (g << (lq + 2)) + tloc;
      int m1 = tloc << twsh;
      float2 a = z[base];
      float2 b = cmulc(z[base + q],   twget(T, m1));
      float2 c = cmulc(z[base + 2*q], twget(T, 2*m1));
      float2 d = cmulc(z[base + 3*q], twget(T, 3*m1));
      float2 s0 = cadd(a, c), s1 = csub(a, c);
      float2 s2 = cadd(b, d), s3 = csub(b, d);
      z[base]       = cadd(s0, s2);
      z[base + q]   = make_float2(s1.x - s3.y, s1.y + s3.x);
      z[base + 2*q] = csub(s0, s2);
      z[base + 3*q] = make_float2(s1.x + s3.y, s1.y - s3.x);
    }
    __syncthreads();
  }
}

// ---------------------------------------------------------------------------
// 1) filter MLP trunk -> h2 [8192][128] (aliases W2T region; runs first)
__global__ __launch_bounds__(256) void mlp_kernel(const float* __restrict__ fw1, const float* __restrict__ fb1,
                                                  const float* __restrict__ fw2, const float* __restrict__ fb2,
                                                  float* __restrict__ h2) {
  __shared__ float sw2[64 * 128];
  __shared__ float sw1[64], sb1[64], sb2[128];
  int t = threadIdx.x;
  for (int i = t; i < 64 * 128; i += 256) sw2[i] = fw2[i];
  if (t < 64)  { sw1[t] = fw1[t]; sb1[t] = fb1[t]; }
  if (t < 128) sb2[t] = fb2[t];
  __syncthreads();
  int l = blockIdx.x * 256 + t;
  float pos = (float)l / 8191.0f;
  float h1[64];
  #pragma unroll
  for (int j = 0; j < 64; ++j) {
    float xx = pos * sw1[j] + sb1[j];
    h1[j] = 0.5f * xx * (1.0f + erff(xx * 0.7071067811865475f));
  }
  for (int m = 0; m < 128; ++m) {
    float acc = sb2[m];
    #pragma unroll
    for (int j = 0; j < 64; ++j) acc += h1[j] * sw2[j * 128 + m];
    h2[(size_t)l * 128 + m] = 0.5f * acc * (1.0f + erff(acc * 0.7071067811865475f));
  }
}

// ---------------------------------------------------------------------------
// 2) coef GEMM (fp32): h2(8192x128) @ fw3[:,2c+1] + fb3[2c+1] -> coefs_t[c][l]
__global__ __launch_bounds__(256) void gemm_coefs_kernel(const float* __restrict__ H2,
    const float* __restrict__ FW3, const float* __restrict__ FB3,
    float* __restrict__ coefs) {
  __shared__ float As[16 * 72];
  __shared__ float Bs[16 * 72];
  int t  = threadIdx.x;
  int n0 = blockIdx.x * 64;   // channel tile
  int m0 = blockIdx.y * 64;   // l tile
  int tr = t >> 4, tc = t & 15;
  float acc[4][4] = {};
  int am = t >> 2, ak = (t & 3) * 4;
  int bk = t >> 4, bn = (t & 15) * 4;
  for (int k0 = 0; k0 < 128; k0 += 16) {
    float4 a = *(const float4*)&H2[(size_t)(m0 + am) * 128 + k0 + ak];
    float b0 = FW3[(size_t)(k0 + bk) * 2048 + 2 * (n0 + bn + 0) + 1];
    float b1 = FW3[(size_t)(k0 + bk) * 2048 + 2 * (n0 + bn + 1) + 1];
    float b2 = FW3[(size_t)(k0 + bk) * 2048 + 2 * (n0 + bn + 2) + 1];
    float b3 = FW3[(size_t)(k0 + bk) * 2048 + 2 * (n0 + bn + 3) + 1];
    __syncthreads();
    As[(ak + 0) * 72 + am] = a.x;
    As[(ak + 1) * 72 + am] = a.y;
    As[(ak + 2) * 72 + am] = a.z;
    As[(ak + 3) * 72 + am] = a.w;
    Bs[bk * 72 + bn + 0] = b0;
    Bs[bk * 72 + bn + 1] = b1;
    Bs[bk * 72 + bn + 2] = b2;
    Bs[bk * 72 + bn + 3] = b3;
    __syncthreads();
    #pragma unroll
    for (int kk = 0; kk < 16; ++kk) {
      float4 av = *(const float4*)&As[kk * 72 + tr * 4];
      float4 bv = *(const float4*)&Bs[kk * 72 + tc * 4];
      float aa[4] = {av.x, av.y, av.z, av.w};
      float bb[4] = {bv.x, bv.y, bv.z, bv.w};
      #pragma unroll
      for (int i = 0; i < 4; ++i)
        #pragma unroll
        for (int j = 0; j < 4; ++j)
          acc[i][j] += aa[i] * bb[j];
    }
  }
  #pragma unroll
  for (int j = 0; j < 4; ++j) {
    int c = n0 + tc * 4 + j;
    float bias = FB3[2 * c + 1];
    float4 val = make_float4(acc[0][j] + bias, acc[1][j] + bias, acc[2][j] + bias, acc[3][j] + bias);
    *(float4*)&coefs[(size_t)c * Lseq + m0 + tr * 4] = val;
  }
}

// ---------------------------------------------------------------------------
// 3) compact+transpose+split in_proj weights: keep cols 3c (v) / 3c+2 (gate),
//    emit W2T hi/lo bf16 [2048 n][1024 k] + b2 fp32.
__global__ __launch_bounds__(256) void compact_w_kernel(const float* __restrict__ w, const float* __restrict__ b,
    unsigned short* __restrict__ w2h, unsigned short* __restrict__ w2l, float* __restrict__ b2) {
  __shared__ float t[64 * 65];
  int n0 = blockIdx.x * 64;
  int k0 = blockIdx.y * 64;
  int tid = threadIdx.x;
  #pragma unroll
  for (int i = 0; i < 16; ++i) {
    int idx = tid + i * 256;
    int nr = idx & 63, kr = idx >> 6;
    int n = n0 + nr;
    int src = (n < 1024) ? 3 * n : 3 * (n - 1024) + 2;
    t[nr * 65 + kr] = w[(size_t)(k0 + kr) * 3072 + src];
  }
  __syncthreads();
  #pragma unroll
  for (int i = 0; i < 16; ++i) {
    int idx = tid + i * 256;
    int kr = idx & 63, nr = idx >> 6;
    float v = t[nr * 65 + kr];
    unsigned short h = f2bf(v);
    size_t o = (size_t)(n0 + nr) * 1024 + k0 + kr;
    w2h[o] = h;
    w2l[o] = f2bf(v - bf2f(h));
  }
  if (blockIdx.y == 0 && tid < 64) {
    int n = n0 + tid;
    int src = (n < 1024) ? 3 * n : 3 * (n - 1024) + 2;
    b2[n] = b[src];
  }
}

// ---------------------------------------------------------------------------
// 4) transpose+split out_w [1024 k][1024 n] -> WoT hi/lo bf16 [n][k]
__global__ __launch_bounds__(256) void wout_t_kernel(const float* __restrict__ w,
    unsigned short* __restrict__ wh, unsigned short* __restrict__ wl) {
  __shared__ float t[64 * 65];
  int n0 = blockIdx.x * 64, k0 = blockIdx.y * 64;
  int tid = threadIdx.x;
  #pragma unroll
  for (int i = 0; i < 16; ++i) {
    int idx = tid + i * 256;
    int nr = idx & 63, kr = idx >> 6;
    t[nr * 65 + kr] = w[(size_t)(k0 + kr) * 1024 + n0 + nr];
  }
  __syncthreads();
  #pragma unroll
  for (int i = 0; i < 16; ++i) {
    int idx = tid + i * 256;
    int kr = idx & 63, nr = idx >> 6;
    float v = t[nr * 65 + kr];
    unsigned short h = f2bf(v);
    size_t o = (size_t)(n0 + nr) * 1024 + k0 + kr;
    wh[o] = h;
    wl[o] = f2bf(v - bf2f(h));
  }
}

// ---------------------------------------------------------------------------
// 5) split x fp32 -> Xhi/Xlo bf16 (same [m][k] layout), into d_out scratch
__global__ __launch_bounds__(256) void convert_x_kernel(const float* __restrict__ x,
    unsigned short* __restrict__ xhi, unsigned short* __restrict__ xlo) {
  size_t i = (size_t)blockIdx.x * 256 + threadIdx.x;
  size_t stride = (size_t)gridDim.x * 256;
  size_t n4 = (size_t)BL * 1024 / 4;
  for (; i < n4; i += stride) {
    float4 v = *(const float4*)&x[i * 4];
    ushort4 h, l;
    h.x = f2bf(v.x); l.x = f2bf(v.x - bf2f(h.x));
    h.y = f2bf(v.y); l.y = f2bf(v.y - bf2f(h.y));
    h.z = f2bf(v.z); l.z = f2bf(v.z - bf2f(h.z));
    h.w = f2bf(v.w); l.w = f2bf(v.w - bf2f(h.w));
    *(ushort4*)&xhi[i * 4] = h;
    *(ushort4*)&xlo[i * 4] = l;
  }
}

// ---------------------------------------------------------------------------
// 6) transpose+split y fp32 [1024 c][BL m] -> Yhi/Ylo bf16 [m][c] (into dead v region)
__global__ __launch_bounds__(256) void transpose_y_kernel(const float* __restrict__ y,
    unsigned short* __restrict__ yh, unsigned short* __restrict__ yl) {
  __shared__ float t[64 * 65];
  int m0 = blockIdx.x * 64, c0 = blockIdx.y * 64;
  int tid = threadIdx.x;
  #pragma unroll
  for (int i = 0; i < 16; ++i) {
    int idx = tid + i * 256;
    int mr = idx & 63, cr = idx >> 6;
    t[cr * 65 + mr] = y[(size_t)(c0 + cr) * BL + m0 + mr];
  }
  __syncthreads();
  #pragma unroll
  for (int i = 0; i < 16; ++i) {
    int idx = tid + i * 256;
    int cr = idx & 63, mr = idx >> 6;
    float v = t[cr * 65 + mr];
    unsigned short h = f2bf(v);
    size_t o = (size_t)(m0 + mr) * 1024 + c0 + cr;
    yh[o] = h;
    yl[o] = f2bf(v - bf2f(h));
  }
}

// ---------------------------------------------------------------------------
// 7) split-bf16 MFMA GEMM template: C[row][col] = sum_k A[row][k]*B[col][k]
//    (both operands K-major).  128x128 tile, 4 waves, 16x16x32 bf16 MFMA,
//    3-product split (hh + hl + lh).  BIAS_MODE: 0 = bias[row], 1 = bias[col].
template<int BIAS_MODE>
__global__ __launch_bounds__(256) void gemm_bt_mfma(
    const unsigned short* __restrict__ Ahi, const unsigned short* __restrict__ Alo,
    const unsigned short* __restrict__ Bhi, const unsigned short* __restrict__ Blo,
    float* __restrict__ Cc, size_t ldc, const float* __restrict__ bias) {
  __shared__ unsigned short lds[4][128 * 32];   // Ahi, Alo, Bhi, Blo tiles (8 KB each)
  int tid  = threadIdx.x;
  int lane = tid & 63;
  int wid  = tid >> 6;
  int wr = wid >> 1, wc = wid & 1;
  size_t row0 = (size_t)blockIdx.y * 128;
  size_t col0 = (size_t)blockIdx.x * 128;

  f32x4 acc[4][4];
  #pragma unroll
  for (int i = 0; i < 4; ++i)
    #pragma unroll
    for (int j = 0; j < 4; ++j) acc[i][j] = (f32x4){0.f, 0.f, 0.f, 0.f};

  const unsigned short* srcs[4] = {Ahi + row0 * KK, Alo + row0 * KK,
                                   Bhi + col0 * KK, Blo + col0 * KK};
  int ko = (lane >> 4) * 8;

  for (int k0 = 0; k0 < KK; k0 += 32) {
    #pragma unroll
    for (int t4 = 0; t4 < 4; ++t4) {
      const unsigned short* sp = srcs[t4] + k0;
      #pragma unroll
      for (int h = 0; h < 2; ++h) {
        int q = h * 256 + tid;                  // 0..511: 16B chunks of the 8 KB tile
        int r = q >> 2, kp = (q & 3) * 8;
        gload_lds16(sp + (size_t)r * KK + kp, &lds[t4][q * 8]);
      }
    }
    __syncthreads();
    bf16x8 ah[4], al[4], bh[4], bl[4];
    #pragma unroll
    for (int f = 0; f < 4; ++f) {
      int ra = wr * 64 + f * 16 + (lane & 15);
      int rb = wc * 64 + f * 16 + (lane & 15);
      ah[f] = *(const bf16x8*)&lds[0][ra * 32 + ko];
      al[f] = *(const bf16x8*)&lds[1][ra * 32 + ko];
      bh[f] = *(const bf16x8*)&lds[2][rb * 32 + ko];
      bl[f] = *(const bf16x8*)&lds[3][rb * 32 + ko];
    }
    #pragma unroll
    for (int i = 0; i < 4; ++i)
      #pragma unroll
      for (int j = 0; j < 4; ++j) {
        acc[i][j] = __builtin_amdgcn_mfma_f32_16x16x32_bf16(ah[i], bh[j], acc[i][j], 0, 0, 0);
        acc[i][j] = __builtin_amdgcn_mfma_f32_16x16x32_bf16(ah[i], bl[j], acc[i][j], 0, 0, 0);
        acc[i][j] = __builtin_amdgcn_mfma_f32_16x16x32_bf16(al[i], bh[j], acc[i][j], 0, 0, 0);
      }
    __syncthreads();
  }

  #pragma unroll
  for (int i = 0; i < 4; ++i) {
    #pragma unroll
    for (int rr = 0; rr < 4; ++rr) {
      size_t row = row0 + wr * 64 + i * 16 + (lane >> 4) * 4 + rr;
      float rb = (BIAS_MODE == 0) ? bias[row] : 0.f;
      #pragma unroll
      for (int j = 0; j < 4; ++j) {
        size_t col = col0 + wc * 64 + j * 16 + (lane & 15);
        float cb = (BIAS_MODE == 1) ? bias[col] : rb;
        Cc[row * ldc + col] = acc[i][j][rr] + cb;
      }
    }
  }
}

// ---------------------------------------------------------------------------
// 8) per-channel FFT conv (unchanged from R0)
__global__ __launch_bounds__(512) void conv_fft_kernel(
    const float* __restrict__ vt, float* __restrict__ x2t,
    const float* __restrict__ coefs,
    const float* __restrict__ short_w, const float* __restrict__ short_b) {
  extern __shared__ char smem[];
  float2* z = (float2*)smem;
  float2* T = (float2*)(smem + (size_t)NF * sizeof(float2));
  int t = threadIdx.x;
  int c = blockIdx.x;

  for (int k = t; k <= 2048; k += 512) {
    double ang = 6.283185307179586 * (double)k / (double)NF;
    T[k] = make_float2((float)cos(ang), (float)sin(ang));
  }
  __syncthreads();

  const float* cf = coefs + (size_t)c * Lseq;
  for (int l = t; l < Lseq; l += 512)      z[l] = make_float2(cf[l], 0.f);
  for (int l = Lseq + t; l < NF; l += 512) z[l] = make_float2(0.f, 0.f);
  __syncthreads();
  fftDIF(z, T, t);

  float2 Hreg[32];
  constexpr float invN = 1.0f / (float)NF;
  #pragma unroll
  for (int j = 0; j < 32; ++j) {
    float2 h = z[t + 512 * j];
    Hreg[j] = make_float2(h.x * invN, h.y * invN);
  }
  __syncthreads();

  float sw0 = short_w[c * 3 + 0], sw1 = short_w[c * 3 + 1], sw2 = short_w[c * 3 + 2];
  float sbv = short_b[c];
  const float* v0 = vt + (size_t)c * BL;
  const float* v1 = v0 + Lseq;
  for (int l = t; l < Lseq; l += 512) {
    float a0 = (l > 0)        ? v0[l - 1] : 0.f;
    float b0 = v0[l];
    float c0 = (l < Lseq - 1) ? v0[l + 1] : 0.f;
    float a1 = (l > 0)        ? v1[l - 1] : 0.f;
    float b1 = v1[l];
    float c1 = (l < Lseq - 1) ? v1[l + 1] : 0.f;
    z[l] = make_float2(sw0 * a0 + sw1 * b0 + sw2 * c0 + sbv,
                       sw0 * a1 + sw1 * b1 + sw2 * c1 + sbv);
  }
  for (int l = Lseq + t; l < NF; l += 512) z[l] = make_float2(0.f, 0.f);
  __syncthreads();
  fftDIF(z, T, t);

  #pragma unroll
  for (int j = 0; j < 32; ++j) {
    int p = t + 512 * j;
    z[p] = cmul(z[p], Hreg[j]);
  }
  __syncthreads();
  fftDIT(z, T, t);

  float* y0 = x2t + (size_t)c * BL;
  float* y1 = y0 + Lseq;
  for (int l = t; l < Lseq; l += 512) {
    float2 cv = z[l];
    y0[l] = y0[l] * cv.x;
    y1[l] = y1[l] * cv.y;
  }
}

// ---------------------------------------------------------------------------
extern "C" void kernel_launch(void* const* d_in, const int* in_sizes, int n_in,
                              void* d_out, int out_size, void* d_ws, size_t ws_size,
                              hipStream_t stream) {
  (void)in_sizes; (void)n_in; (void)out_size;
  const float* x    = (const float*)d_in[0];
  const float* ipw  = (const float*)d_in[1];
  const float* ipb  = (const float*)d_in[2];
  const float* sw   = (const float*)d_in[3];
  const float* sb   = (const float*)d_in[4];
  const float* fw1  = (const float*)d_in[5];
  const float* fb1  = (const float*)d_in[6];
  const float* fw2  = (const float*)d_in[7];
  const float* fb2  = (const float*)d_in[8];
  const float* fw3  = (const float*)d_in[9];
  const float* fb3  = (const float*)d_in[10];
  const float* outw = (const float*)d_in[11];
  const float* outb = (const float*)d_in[12];
  float* out = (float*)d_out;
  float* ws  = (float*)d_ws;

  if (ws_size < WS_FLOATS * 4) return;

  float*          big   = ws + BIG_OFF;                    // [2048][BL] fp32
  float*          vt    = big;                             // rows 0..1023
  float*          x2t   = big + (size_t)Cd * BL;           // rows 1024..2047
  float*          coefs = ws + COEF_OFF;
  unsigned short* w2h   = (unsigned short*)(ws + W2TH_OFF);
  unsigned short* w2l   = (unsigned short*)(ws + W2TL_OFF);
  unsigned short* woh   = (unsigned short*)(ws + WOTH_OFF);
  unsigned short* wol   = (unsigned short*)(ws + WOTL_OFF);
  float*          b2    = ws + B2_OFF;
  float*          h2    = ws + W2TH_OFF;                   // transient alias (consumed before compact_w)
  unsigned short* xhi   = (unsigned short*)d_out;          // d_out scratch, dead until final GEMM
  unsigned short* xlo   = xhi + (size_t)BL * 1024;
  unsigned short* yhi   = (unsigned short*)big;            // overwrites dead v region after conv_fft
  unsigned short* ylo   = yhi + (size_t)BL * 1024;

  constexpr int CONV_LDS = NF * 8 + 2049 * 8;  // 147464 B
  hipFuncSetAttribute(reinterpret_cast<const void*>(conv_fft_kernel),
                      hipFuncAttributeMaxDynamicSharedMemorySize, CONV_LDS);

  // h2 aliases W2T region -> mlp + coefs GEMM must precede compact_w.
  mlp_kernel<<<32, 256, 0, stream>>>(fw1, fb1, fw2, fb2, h2);
  gemm_coefs_kernel<<<dim3(16, 128), 256, 0, stream>>>(h2, fw3, fb3, coefs);
  compact_w_kernel<<<dim3(32, 16), 256, 0, stream>>>(ipw, ipb, w2h, w2l, b2);
  wout_t_kernel<<<dim3(16, 16), 256, 0, stream>>>(outw, woh, wol);
  convert_x_kernel<<<2048, 256, 0, stream>>>(x, xhi, xlo);
  // in_proj: rows = 2048 output channels (v | gate), cols = 16384 positions
  gemm_bt_mfma<0><<<dim3(128, 16), 256, 0, stream>>>(w2h, w2l, xhi, xlo, big, (size_t)BL, b2);
  conv_fft_kernel<<<1024, 512, CONV_LDS, stream>>>(vt, x2t, coefs, sw, sb);
  transpose_y_kernel<<<dim3(256, 16), 256, 0, stream>>>(x2t, yhi, ylo);
  // out proj: rows = 16384 positions, cols = 1024 channels
  gemm_bt_mfma<1><<<dim3(8, 128), 256, 0, stream>>>(yhi, ylo, woh, wol, out, (size_t)1024, outb);
}

// Round 3
// 778.928 us; speedup vs baseline: 2.4735x; 1.3165x over previous
//
#include <hip/hip_runtime.h>
#include <math.h>

// ---------------------------------------------------------------------------
// Hyena forward, MI355X.  B=2, L=8192, C=1024, ORDER=2.
// R2: conv_fft rewritten — padded LDS indexing PD(i)=i+(i>>4) kills the
// power-of-2-stride bank conflicts (was 1.0e8 conflicts/dispatch), twiddles
// computed via __sincosf (no table, no double-trig init), 1024 threads/block.
// GEMM path unchanged from R1 (split-bf16 MFMA, 3-product).
// ---------------------------------------------------------------------------

constexpr int Lseq = 8192;
constexpr int Cd   = 1024;
constexpr int BL   = 16384;   // B * L
constexpr int NF   = 16384;   // FFT length = 2L
constexpr int KK   = 1024;    // GEMM K dim (both GEMMs)
constexpr int FT   = 1024;    // conv_fft threads per block

// ws layout (float offsets)
constexpr size_t BIG_OFF  = 0;                                  // [2048][BL] fp32: rows 0-1023 v, 1024-2047 gate->y
constexpr size_t COEF_OFF = BIG_OFF + (size_t)2048 * BL;
constexpr size_t W2TH_OFF = COEF_OFF + (size_t)Cd * Lseq;
constexpr size_t W2TL_OFF = W2TH_OFF + (size_t)2048 * 1024 / 2;
constexpr size_t WOTH_OFF = W2TL_OFF + (size_t)2048 * 1024 / 2;
constexpr size_t WOTL_OFF = WOTH_OFF + (size_t)1024 * 1024 / 2;
constexpr size_t B2_OFF   = WOTL_OFF + (size_t)1024 * 1024 / 2;
constexpr size_t WS_FLOATS = B2_OFF + 2048;                     // 180,363,264 B

using bf16x8 = __attribute__((ext_vector_type(8))) short;
using f32x4  = __attribute__((ext_vector_type(4))) float;

__device__ inline unsigned short f2bf(float f) {
  unsigned u = __float_as_uint(f);
  u += 0x7FFFu + ((u >> 16) & 1u);
  return (unsigned short)(u >> 16);
}
__device__ inline float bf2f(unsigned short h) { return __uint_as_float(((unsigned)h) << 16); }

__device__ inline void gload_lds16(const void* g, void* l) {
  __builtin_amdgcn_global_load_lds((const __attribute__((address_space(1))) unsigned int*)g,
                                   (__attribute__((address_space(3))) unsigned int*)l, 16, 0, 0);
}

// ---------------------------------------------------------------------------
// complex helpers
__device__ inline float2 cadd(float2 a, float2 b){ return make_float2(a.x+b.x, a.y+b.y); }
__device__ inline float2 csub(float2 a, float2 b){ return make_float2(a.x-b.x, a.y-b.y); }
__device__ inline float2 cmul(float2 a, float2 b){ return make_float2(a.x*b.x - a.y*b.y, a.x*b.y + a.y*b.x); }
__device__ inline float2 cmulc(float2 a, float2 w){ return make_float2(a.x*w.x + a.y*w.y, a.y*w.x - a.x*w.y); }

// padded LDS index: 1 float2 pad per 16 -> all radix-4 stride patterns land on
// the uniform 4-way minimum for wave64 ds_read_b64 (conflict-free).
__device__ inline int PD(int i) { return i + (i >> 4); }

// W_N^m = e^{-2*pi*i*m/16384}, computed (fast sincos), no table.
__device__ inline float2 twW(int m) {
  float s, c;
  __sincosf((float)m * -3.8349519697141029e-4f, &s, &c);   // -2*pi/16384
  return make_float2(c, s);
}

// radix-4 DIF, natural in -> digit-reversed out.  FT threads, padded z.
__device__ inline void fftDIF(float2* __restrict__ z, int t) {
  for (int lq = 12; lq >= 0; lq -= 2) {
    int q    = 1 << lq;
    int twsh = 12 - lq;
    #pragma unroll
    for (int mb = 0; mb < 4; ++mb) {
      int m    = t + mb * FT;
      int tloc = m & (q - 1);
      int g    = m >> lq;
      int base = (g << (lq + 2)) + tloc;
      int i0 = PD(base), i1 = PD(base + q), i2 = PD(base + 2*q), i3 = PD(base + 3*q);
      float2 a = z[i0], b = z[i1], c = z[i2], d = z[i3];
      float2 t0 = cadd(a, c), t1 = csub(a, c);
      float2 t2 = cadd(b, d), t3 = csub(b, d);
      float2 y0 = cadd(t0, t2);
      float2 y2 = csub(t0, t2);
      float2 y1 = make_float2(t1.x + t3.y, t1.y - t3.x);   // t1 - i*t3
      float2 y3 = make_float2(t1.x - t3.y, t1.y + t3.x);   // t1 + i*t3
      int m1 = tloc << twsh;
      float2 w1 = twW(m1);
      float2 w2 = make_float2(w1.x*w1.x - w1.y*w1.y, 2.f*w1.x*w1.y);
      float2 w3 = cmul(w1, w2);
      z[i0] = y0;
      z[i1] = cmul(y1, w1);
      z[i2] = cmul(y2, w2);
      z[i3] = cmul(y3, w3);
    }
    __syncthreads();
  }
}

// radix-4 DIT inverse (digit-reversed in -> natural out), unscaled (x N).
__device__ inline void fftDIT(float2* __restrict__ z, int t) {
  for (int lq = 0; lq <= 12; lq += 2) {
    int q    = 1 << lq;
    int twsh = 12 - lq;
    #pragma unroll
    for (int mb = 0; mb < 4; ++mb) {
      int m    = t + mb * FT;
      int tloc = m & (q - 1);
      int g    = m >> lq;
      int base = (g << (lq + 2)) + tloc;
      int i0 = PD(base), i1 = PD(base + q), i2 = PD(base + 2*q), i3 = PD(base + 3*q);
      int m1 = tloc << twsh;
      float2 w1 = twW(m1);
      float2 w2 = make_float2(w1.x*w1.x - w1.y*w1.y, 2.f*w1.x*w1.y);
      float2 w3 = cmul(w1, w2);
      float2 a = z[i0];
      float2 b = cmulc(z[i1], w1);
      float2 c = cmulc(z[i2], w2);
      float2 d = cmulc(z[i3], w3);
      float2 s0 = cadd(a, c), s1 = csub(a, c);
      float2 s2 = cadd(b, d), s3 = csub(b, d);
      z[i0] = cadd(s0, s2);
      z[i1] = make_float2(s1.x - s3.y, s1.y + s3.x);  // s1 + i*s3
      z[i2] = csub(s0, s2);
      z[i3] = make_float2(s1.x + s3.y, s1.y - s3.x);  // s1 - i*s3
    }
    __syncthreads();
  }
}

// ---------------------------------------------------------------------------
// 1) filter MLP trunk -> h2 [8192][128] (aliases W2T region; runs first)
__global__ __launch_bounds__(256) void mlp_kernel(const float* __restrict__ fw1, const float* __restrict__ fb1,
                                                  const float* __restrict__ fw2, const float* __restrict__ fb2,
                                                  float* __restrict__ h2) {
  __shared__ float sw2[64 * 128];
  __shared__ float sw1[64], sb1[64], sb2[128];
  int t = threadIdx.x;
  for (int i = t; i < 64 * 128; i += 256) sw2[i] = fw2[i];
  if (t < 64)  { sw1[t] = fw1[t]; sb1[t] = fb1[t]; }
  if (t < 128) sb2[t] = fb2[t];
  __syncthreads();
  int l = blockIdx.x * 256 + t;
  float pos = (float)l / 8191.0f;
  float h1[64];
  #pragma unroll
  for (int j = 0; j < 64; ++j) {
    float xx = pos * sw1[j] + sb1[j];
    h1[j] = 0.5f * xx * (1.0f + erff(xx * 0.7071067811865475f));
  }
  for (int m = 0; m < 128; ++m) {
    float acc = sb2[m];
    #pragma unroll
    for (int j = 0; j < 64; ++j) acc += h1[j] * sw2[j * 128 + m];
    h2[(size_t)l * 128 + m] = 0.5f * acc * (1.0f + erff(acc * 0.7071067811865475f));
  }
}

// ---------------------------------------------------------------------------
// 2) coef GEMM (fp32): h2(8192x128) @ fw3[:,2c+1] + fb3[2c+1] -> coefs_t[c][l]
__global__ __launch_bounds__(256) void gemm_coefs_kernel(const float* __restrict__ H2,
    const float* __restrict__ FW3, const float* __restrict__ FB3,
    float* __restrict__ coefs) {
  __shared__ float As[16 * 72];
  __shared__ float Bs[16 * 72];
  int t  = threadIdx.x;
  int n0 = blockIdx.x * 64;   // channel tile
  int m0 = blockIdx.y * 64;   // l tile
  int tr = t >> 4, tc = t & 15;
  float acc[4][4] = {};
  int am = t >> 2, ak = (t & 3) * 4;
  int bk = t >> 4, bn = (t & 15) * 4;
  for (int k0 = 0; k0 < 128; k0 += 16) {
    float4 a = *(const float4*)&H2[(size_t)(m0 + am) * 128 + k0 + ak];
    float b0 = FW3[(size_t)(k0 + bk) * 2048 + 2 * (n0 + bn + 0) + 1];
    float b1 = FW3[(size_t)(k0 + bk) * 2048 + 2 * (n0 + bn + 1) + 1];
    float b2 = FW3[(size_t)(k0 + bk) * 2048 + 2 * (n0 + bn + 2) + 1];
    float b3 = FW3[(size_t)(k0 + bk) * 2048 + 2 * (n0 + bn + 3) + 1];
    __syncthreads();
    As[(ak + 0) * 72 + am] = a.x;
    As[(ak + 1) * 72 + am] = a.y;
    As[(ak + 2) * 72 + am] = a.z;
    As[(ak + 3) * 72 + am] = a.w;
    Bs[bk * 72 + bn + 0] = b0;
    Bs[bk * 72 + bn + 1] = b1;
    Bs[bk * 72 + bn + 2] = b2;
    Bs[bk * 72 + bn + 3] = b3;
    __syncthreads();
    #pragma unroll
    for (int kk = 0; kk < 16; ++kk) {
      float4 av = *(const float4*)&As[kk * 72 + tr * 4];
      float4 bv = *(const float4*)&Bs[kk * 72 + tc * 4];
      float aa[4] = {av.x, av.y, av.z, av.w};
      float bb[4] = {bv.x, bv.y, bv.z, bv.w};
      #pragma unroll
      for (int i = 0; i < 4; ++i)
        #pragma unroll
        for (int j = 0; j < 4; ++j)
          acc[i][j] += aa[i] * bb[j];
    }
  }
  #pragma unroll
  for (int j = 0; j < 4; ++j) {
    int c = n0 + tc * 4 + j;
    float bias = FB3[2 * c + 1];
    float4 val = make_float4(acc[0][j] + bias, acc[1][j] + bias, acc[2][j] + bias, acc[3][j] + bias);
    *(float4*)&coefs[(size_t)c * Lseq + m0 + tr * 4] = val;
  }
}

// ---------------------------------------------------------------------------
// 3) compact+transpose+split in_proj weights
__global__ __launch_bounds__(256) void compact_w_kernel(const float* __restrict__ w, const float* __restrict__ b,
    unsigned short* __restrict__ w2h, unsigned short* __restrict__ w2l, float* __restrict__ b2) {
  __shared__ float t[64 * 65];
  int n0 = blockIdx.x * 64;
  int k0 = blockIdx.y * 64;
  int tid = threadIdx.x;
  #pragma unroll
  for (int i = 0; i < 16; ++i) {
    int idx = tid + i * 256;
    int nr = idx & 63, kr = idx >> 6;
    int n = n0 + nr;
    int src = (n < 1024) ? 3 * n : 3 * (n - 1024) + 2;
    t[nr * 65 + kr] = w[(size_t)(k0 + kr) * 3072 + src];
  }
  __syncthreads();
  #pragma unroll
  for (int i = 0; i < 16; ++i) {
    int idx = tid + i * 256;
    int kr = idx & 63, nr = idx >> 6;
    float v = t[nr * 65 + kr];
    unsigned short h = f2bf(v);
    size_t o = (size_t)(n0 + nr) * 1024 + k0 + kr;
    w2h[o] = h;
    w2l[o] = f2bf(v - bf2f(h));
  }
  if (blockIdx.y == 0 && tid < 64) {
    int n = n0 + tid;
    int src = (n < 1024) ? 3 * n : 3 * (n - 1024) + 2;
    b2[n] = b[src];
  }
}

// ---------------------------------------------------------------------------
// 4) transpose+split out_w -> WoT hi/lo bf16 [n][k]
__global__ __launch_bounds__(256) void wout_t_kernel(const float* __restrict__ w,
    unsigned short* __restrict__ wh, unsigned short* __restrict__ wl) {
  __shared__ float t[64 * 65];
  int n0 = blockIdx.x * 64, k0 = blockIdx.y * 64;
  int tid = threadIdx.x;
  #pragma unroll
  for (int i = 0; i < 16; ++i) {
    int idx = tid + i * 256;
    int nr = idx & 63, kr = idx >> 6;
    t[nr * 65 + kr] = w[(size_t)(k0 + kr) * 1024 + n0 + nr];
  }
  __syncthreads();
  #pragma unroll
  for (int i = 0; i < 16; ++i) {
    int idx = tid + i * 256;
    int kr = idx & 63, nr = idx >> 6;
    float v = t[nr * 65 + kr];
    unsigned short h = f2bf(v);
    size_t o = (size_t)(n0 + nr) * 1024 + k0 + kr;
    wh[o] = h;
    wl[o] = f2bf(v - bf2f(h));
  }
}

// ---------------------------------------------------------------------------
// 5) split x fp32 -> Xhi/Xlo bf16, into d_out scratch
__global__ __launch_bounds__(256) void convert_x_kernel(const float* __restrict__ x,
    unsigned short* __restrict__ xhi, unsigned short* __restrict__ xlo) {
  size_t i = (size_t)blockIdx.x * 256 + threadIdx.x;
  size_t stride = (size_t)gridDim.x * 256;
  size_t n4 = (size_t)BL * 1024 / 4;
  for (; i < n4; i += stride) {
    float4 v = *(const float4*)&x[i * 4];
    ushort4 h, l;
    h.x = f2bf(v.x); l.x = f2bf(v.x - bf2f(h.x));
    h.y = f2bf(v.y); l.y = f2bf(v.y - bf2f(h.y));
    h.z = f2bf(v.z); l.z = f2bf(v.z - bf2f(h.z));
    h.w = f2bf(v.w); l.w = f2bf(v.w - bf2f(h.w));
    *(ushort4*)&xhi[i * 4] = h;
    *(ushort4*)&xlo[i * 4] = l;
  }
}

// ---------------------------------------------------------------------------
// 6) transpose+split y fp32 [1024 c][BL m] -> Yhi/Ylo bf16 [m][c]
__global__ __launch_bounds__(256) void transpose_y_kernel(const float* __restrict__ y,
    unsigned short* __restrict__ yh, unsigned short* __restrict__ yl) {
  __shared__ float t[64 * 65];
  int m0 = blockIdx.x * 64, c0 = blockIdx.y * 64;
  int tid = threadIdx.x;
  #pragma unroll
  for (int i = 0; i < 16; ++i) {
    int idx = tid + i * 256;
    int mr = idx & 63, cr = idx >> 6;
    t[cr * 65 + mr] = y[(size_t)(c0 + cr) * BL + m0 + mr];
  }
  __syncthreads();
  #pragma unroll
  for (int i = 0; i < 16; ++i) {
    int idx = tid + i * 256;
    int cr = idx & 63, mr = idx >> 6;
    float v = t[cr * 65 + mr];
    unsigned short h = f2bf(v);
    size_t o = (size_t)(m0 + mr) * 1024 + c0 + cr;
    yh[o] = h;
    yl[o] = f2bf(v - bf2f(h));
  }
}

// ---------------------------------------------------------------------------
// 7) split-bf16 MFMA GEMM (unchanged from R1)
template<int BIAS_MODE>
__global__ __launch_bounds__(256) void gemm_bt_mfma(
    const unsigned short* __restrict__ Ahi, const unsigned short* __restrict__ Alo,
    const unsigned short* __restrict__ Bhi, const unsigned short* __restrict__ Blo,
    float* __restrict__ Cc, size_t ldc, const float* __restrict__ bias) {
  __shared__ unsigned short lds[4][128 * 32];
  int tid  = threadIdx.x;
  int lane = tid & 63;
  int wid  = tid >> 6;
  int wr = wid >> 1, wc = wid & 1;
  size_t row0 = (size_t)blockIdx.y * 128;
  size_t col0 = (size_t)blockIdx.x * 128;

  f32x4 acc[4][4];
  #pragma unroll
  for (int i = 0; i < 4; ++i)
    #pragma unroll
    for (int j = 0; j < 4; ++j) acc[i][j] = (f32x4){0.f, 0.f, 0.f, 0.f};

  const unsigned short* srcs[4] = {Ahi + row0 * KK, Alo + row0 * KK,
                                   Bhi + col0 * KK, Blo + col0 * KK};
  int ko = (lane >> 4) * 8;

  for (int k0 = 0; k0 < KK; k0 += 32) {
    #pragma unroll
    for (int t4 = 0; t4 < 4; ++t4) {
      const unsigned short* sp = srcs[t4] + k0;
      #pragma unroll
      for (int h = 0; h < 2; ++h) {
        int q = h * 256 + tid;
        int r = q >> 2, kp = (q & 3) * 8;
        gload_lds16(sp + (size_t)r * KK + kp, &lds[t4][q * 8]);
      }
    }
    __syncthreads();
    bf16x8 ah[4], al[4], bh[4], bl[4];
    #pragma unroll
    for (int f = 0; f < 4; ++f) {
      int ra = wr * 64 + f * 16 + (lane & 15);
      int rb = wc * 64 + f * 16 + (lane & 15);
      ah[f] = *(const bf16x8*)&lds[0][ra * 32 + ko];
      al[f] = *(const bf16x8*)&lds[1][ra * 32 + ko];
      bh[f] = *(const bf16x8*)&lds[2][rb * 32 + ko];
      bl[f] = *(const bf16x8*)&lds[3][rb * 32 + ko];
    }
    #pragma unroll
    for (int i = 0; i < 4; ++i)
      #pragma unroll
      for (int j = 0; j < 4; ++j) {
        acc[i][j] = __builtin_amdgcn_mfma_f32_16x16x32_bf16(ah[i], bh[j], acc[i][j], 0, 0, 0);
        acc[i][j] = __builtin_amdgcn_mfma_f32_16x16x32_bf16(ah[i], bl[j], acc[i][j], 0, 0, 0);
        acc[i][j] = __builtin_amdgcn_mfma_f32_16x16x32_bf16(al[i], bh[j], acc[i][j], 0, 0, 0);
      }
    __syncthreads();
  }

  #pragma unroll
  for (int i = 0; i < 4; ++i) {
    #pragma unroll
    for (int rr = 0; rr < 4; ++rr) {
      size_t row = row0 + wr * 64 + i * 16 + (lane >> 4) * 4 + rr;
      float rb = (BIAS_MODE == 0) ? bias[row] : 0.f;
      #pragma unroll
      for (int j = 0; j < 4; ++j) {
        size_t col = col0 + wc * 64 + j * 16 + (lane & 15);
        float cb = (BIAS_MODE == 1) ? bias[col] : rb;
        Cc[row * ldc + col] = acc[i][j][rr] + cb;
      }
    }
  }
}

// ---------------------------------------------------------------------------
// 8) per-channel FFT conv: padded LDS, computed twiddles, 1024 threads.
__global__ __launch_bounds__(FT) void conv_fft_kernel(
    const float* __restrict__ vt, float* __restrict__ x2t,
    const float* __restrict__ coefs,
    const float* __restrict__ short_w, const float* __restrict__ short_b) {
  extern __shared__ float2 z[];      // PD(NF-1)+1 = 17407 -> alloc 17408 float2
  int t = threadIdx.x;
  int c = blockIdx.x;

  // ---- filter FFT
  const float* cf = coefs + (size_t)c * Lseq;
  for (int l = t; l < Lseq; l += FT)      z[PD(l)] = make_float2(cf[l], 0.f);
  for (int l = Lseq + t; l < NF; l += FT) z[PD(l)] = make_float2(0.f, 0.f);
  __syncthreads();
  fftDIF(z, t);

  float2 Hreg[16];
  constexpr float invN = 1.0f / (float)NF;
  #pragma unroll
  for (int j = 0; j < 16; ++j) {
    float2 h = z[PD(t + FT * j)];
    Hreg[j] = make_float2(h.x * invN, h.y * invN);
  }
  __syncthreads();

  // ---- v: short depthwise conv (k=3, same pad), batches packed re/im
  float sw0 = short_w[c * 3 + 0], sw1 = short_w[c * 3 + 1], sw2 = short_w[c * 3 + 2];
  float sbv = short_b[c];
  const float* v0 = vt + (size_t)c * BL;
  const float* v1 = v0 + Lseq;
  for (int l = t; l < Lseq; l += FT) {
    float a0 = (l > 0)        ? v0[l - 1] : 0.f;
    float b0 = v0[l];
    float c0 = (l < Lseq - 1) ? v0[l + 1] : 0.f;
    float a1 = (l > 0)        ? v1[l - 1] : 0.f;
    float b1 = v1[l];
    float c1 = (l < Lseq - 1) ? v1[l + 1] : 0.f;
    z[PD(l)] = make_float2(sw0 * a0 + sw1 * b0 + sw2 * c0 + sbv,
                           sw0 * a1 + sw1 * b1 + sw2 * c1 + sbv);
  }
  for (int l = Lseq + t; l < NF; l += FT) z[PD(l)] = make_float2(0.f, 0.f);
  __syncthreads();
  fftDIF(z, t);

  #pragma unroll
  for (int j = 0; j < 16; ++j) {
    int p = PD(t + FT * j);
    z[p] = cmul(z[p], Hreg[j]);
  }
  __syncthreads();
  fftDIT(z, t);

  // ---- gate and write back in place (y = gate * conv)
  float* y0 = x2t + (size_t)c * BL;
  float* y1 = y0 + Lseq;
  for (int l = t; l < Lseq; l += FT) {
    float2 cv = z[PD(l)];
    y0[l] = y0[l] * cv.x;
    y1[l] = y1[l] * cv.y;
  }
}

// ---------------------------------------------------------------------------
extern "C" void kernel_launch(void* const* d_in, const int* in_sizes, int n_in,
                              void* d_out, int out_size, void* d_ws, size_t ws_size,
                              hipStream_t stream) {
  (void)in_sizes; (void)n_in; (void)out_size;
  const float* x    = (const float*)d_in[0];
  const float* ipw  = (const float*)d_in[1];
  const float* ipb  = (const float*)d_in[2];
  const float* sw   = (const float*)d_in[3];
  const float* sb   = (const float*)d_in[4];
  const float* fw1  = (const float*)d_in[5];
  const float* fb1  = (const float*)d_in[6];
  const float* fw2  = (const float*)d_in[7];
  const float* fb2  = (const float*)d_in[8];
  const float* fw3  = (const float*)d_in[9];
  const float* fb3  = (const float*)d_in[10];
  const float* outw = (const float*)d_in[11];
  const float* outb = (const float*)d_in[12];
  float* out = (float*)d_out;
  float* ws  = (float*)d_ws;

  if (ws_size < WS_FLOATS * 4) return;

  float*          big   = ws + BIG_OFF;
  float*          vt    = big;
  float*          x2t   = big + (size_t)Cd * BL;
  float*          coefs = ws + COEF_OFF;
  unsigned short* w2h   = (unsigned short*)(ws + W2TH_OFF);
  unsigned short* w2l   = (unsigned short*)(ws + W2TL_OFF);
  unsigned short* woh   = (unsigned short*)(ws + WOTH_OFF);
  unsigned short* wol   = (unsigned short*)(ws + WOTL_OFF);
  float*          b2    = ws + B2_OFF;
  float*          h2    = ws + W2TH_OFF;                   // transient alias
  unsigned short* xhi   = (unsigned short*)d_out;
  unsigned short* xlo   = xhi + (size_t)BL * 1024;
  unsigned short* yhi   = (unsigned short*)big;
  unsigned short* ylo   = yhi + (size_t)BL * 1024;

  constexpr int CONV_LDS = 17408 * 8;   // 139,264 B
  hipFuncSetAttribute(reinterpret_cast<const void*>(conv_fft_kernel),
                      hipFuncAttributeMaxDynamicSharedMemorySize, CONV_LDS);

  mlp_kernel<<<32, 256, 0, stream>>>(fw1, fb1, fw2, fb2, h2);
  gemm_coefs_kernel<<<dim3(16, 128), 256, 0, stream>>>(h2, fw3, fb3, coefs);
  compact_w_kernel<<<dim3(32, 16), 256, 0, stream>>>(ipw, ipb, w2h, w2l, b2);
  wout_t_kernel<<<dim3(16, 16), 256, 0, stream>>>(outw, woh, wol);
  convert_x_kernel<<<2048, 256, 0, stream>>>(x, xhi, xlo);
  gemm_bt_mfma<0><<<dim3(128, 16), 256, 0, stream>>>(w2h, w2l, xhi, xlo, big, (size_t)BL, b2);
  conv_fft_kernel<<<1024, FT, CONV_LDS, stream>>>(vt, x2t, coefs, sw, sb);
  transpose_y_kernel<<<dim3(256, 16), 256, 0, stream>>>(x2t, yhi, ylo);
  gemm_bt_mfma<1><<<dim3(8, 128), 256, 0, stream>>>(yhi, ylo, woh, wol, out, (size_t)1024, outb);
}